// Round 1
// baseline (95.368 us; speedup 1.0000x reference)
//
#include <hip/hip_runtime.h>
#include <math.h>

#define TB   256
#define HH   128      // input H=W
#define OHW  64       // output H=W
#define TR   16       // output rows per tile
#define NT   4        // tiles per plane (64/16)
#define XR   37       // input rows staged: 2*TR+5
#define XC   136      // 128 cols + pad (col offset +4, zeros in pad)
#define N0C  68       // n0 tile row stride

__device__ __forceinline__ float sigmoidf(float z) {
    return 1.0f / (1.0f + __expf(-z));
}

__global__ __launch_bounds__(TB) void fused_densenet_kernel(
    const float* __restrict__ x,
    const float* __restrict__ maxgate,
    const float* __restrict__ mb,
    const float* __restrict__ pconvs,
    const float* __restrict__ pbs,
    const float* __restrict__ pgates,
    const float* __restrict__ gbs,
    float* __restrict__ out)
{
    __shared__ float xs[XR][XC];          // input slab, zero-padded
    __shared__ float n0s[TR + 2][N0C];    // n0 with 1-halo (18 x 66 used)

    const int t     = threadIdx.x;
    const int bid   = blockIdx.x;
    const int tile  = bid & (NT - 1);
    const int plane = bid >> 2;           // b*256 + c
    const int c     = plane & 255;
    const int r0    = tile * TR;          // first global output row of tile

    // ---- uniform weights/biases (blockIdx-uniform -> scalar loads) ----
    float wmax[9], wp0[9], wp1[9], wp2[9], wp3[9], wg0[9], wg2[9];
#pragma unroll
    for (int i = 0; i < 9; ++i) {
        wmax[i] = maxgate[c * 9  + i];
        wg0[i]  = pgates [c * 27 + i * 3 + 0];   // leaf0 gate
        wg2[i]  = pgates [c * 27 + i * 3 + 2];   // leaf1 gate AND node gate
        wp0[i]  = pconvs [c * 36 + i * 4 + 0];
        wp1[i]  = pconvs [c * 36 + i * 4 + 1];
        wp2[i]  = pconvs [c * 36 + i * 4 + 2];
        wp3[i]  = pconvs [c * 36 + i * 4 + 3];
    }
    const float bmax = mb[c];
    const float bp0 = pbs[c * 4 + 0], bp1 = pbs[c * 4 + 1];
    const float bp2 = pbs[c * 4 + 2], bp3 = pbs[c * 4 + 3];
    const float bg0 = gbs[c * 3 + 0];   // leaf0 gate bias
    const float bg1 = gbs[c * 3 + 1];   // leaf1 gate bias
    const float bg2 = gbs[c * 3 + 2];   // node gate bias

    // ---- global -> LDS: rows [2*r0-3 , 2*r0+33], cols -4..131 (zero pad) ----
    const float* xplane = x + (size_t)plane * (HH * HH);
    const int ir0 = 2 * r0 - 3;
    for (int s = t; s < XR * 34; s += TB) {       // 34 float4 slots per row
        const int rr = s / 34;
        const int q  = s - rr * 34;
        float4 v = make_float4(0.f, 0.f, 0.f, 0.f);
        const int ir = ir0 + rr;
        if (q >= 1 && q <= 32 && (unsigned)ir < (unsigned)HH) {
            v = *reinterpret_cast<const float4*>(xplane + ir * HH + (q - 1) * 4);
        }
        *reinterpret_cast<float4*>(&xs[rr][q * 4]) = v;   // 16B-aligned
    }
    __syncthreads();

    // ---- halo ring of n0 (18x66 grid minus 16x64 interior = 164 positions) ----
    if (t < 164) {
        int lr, lc;
        if (t < 66)        { lr = 0;  lc = t;       }
        else if (t < 132)  { lr = 17; lc = t - 66;  }
        else { const int i = t - 132; lr = 1 + (i >> 1); lc = (i & 1) ? 65 : 0; }
        const int gr = r0 - 1 + lr;   // global output row of this n0 entry
        const int gc = lc - 1;        // global output col
        float n0v = 0.f;              // stage-2 conv zero-pads n0 at image edge
        if ((unsigned)gr < (unsigned)OHW && (unsigned)gc < (unsigned)OHW) {
            float ag = 0.f, a0 = 0.f, a1 = 0.f;
#pragma unroll
            for (int dr = 0; dr < 3; ++dr)
#pragma unroll
                for (int dc = 0; dc < 3; ++dc) {
                    const float v = xs[2 * lr + dr][2 * lc + dc + 1];
                    const int i = dr * 3 + dc;
                    ag += v * wg0[i];
                    a0 += v * wp0[i];
                    a1 += v * wp1[i];
                }
            const float sg = sigmoidf(ag + bg0);
            n0v = sg * (a0 + bp0) + (1.f - sg) * (a1 + bp1);
        }
        n0s[lr][lc] = n0v;
    }

    // ---- interior: all 7 convs + maxpool from one shared 3x3 window ----
    const int lc64 = t & 63;          // output col (whole wave: same row, cols 0..63)
    const int lrq  = t >> 6;
    float out1[4], n1[4];
#pragma unroll
    for (int k = 0; k < 4; ++k) {
        const int lr = lrq + 4 * k;   // local output row 0..15
        const int gr = r0 + lr;
        const int gc = lc64;

        float w9[9];
#pragma unroll
        for (int dr = 0; dr < 3; ++dr)
#pragma unroll
            for (int dc = 0; dc < 3; ++dc)
                w9[dr * 3 + dc] = xs[2 * lr + dr + 2][2 * lc64 + dc + 3];

        float mp = -INFINITY;
        float amax = 0.f, a0 = 0.f, a1 = 0.f, a2 = 0.f, a3 = 0.f;
        float ag0 = 0.f, ag2 = 0.f;
#pragma unroll
        for (int i = 0; i < 9; ++i) {
            const int dr = i / 3, dc = i % 3;
            const float v = w9[i];
            amax += v * wmax[i];
            a0   += v * wp0[i];
            a1   += v * wp1[i];
            a2   += v * wp2[i];
            a3   += v * wp3[i];
            ag0  += v * wg0[i];
            ag2  += v * wg2[i];
            // maxpool pads with -inf; only low edges can go out of range here
            const bool valid = ((gr > 0) | (dr > 0)) & ((gc > 0) | (dc > 0));
            mp = fmaxf(mp, valid ? v : -INFINITY);
        }
        const float sg0 = sigmoidf(ag0 + bg0);
        n0s[lr + 1][lc64 + 1] = sg0 * (a0 + bp0) + (1.f - sg0) * (a1 + bp1);
        const float sg1 = sigmoidf(ag2 + bg1);          // leaf1 gate: bias gbs[:,1]
        n1[k]   = sg1 * (a2 + bp2) + (1.f - sg1) * (a3 + bp3);
        out1[k] = mp * (amax + bmax);
    }
    __syncthreads();

    // ---- stage 2: node gate conv on n0 (stride 1, pad 1) + combine + store ----
    float* oplane = out + (size_t)plane * (OHW * OHW);
#pragma unroll
    for (int k = 0; k < 4; ++k) {
        const int lr = lrq + 4 * k;
        float ag = 0.f;
#pragma unroll
        for (int dr = 0; dr < 3; ++dr)
#pragma unroll
            for (int dc = 0; dc < 3; ++dc)
                ag += n0s[lr + dr][lc64 + dc] * wg2[dr * 3 + dc];
        const float g   = sigmoidf(ag + bg2);           // node gate: bias gbs[:,2]
        const float n0c = n0s[lr + 1][lc64 + 1];
        oplane[(r0 + lr) * OHW + lc64] = out1[k] + n0c * g + n1[k] * (1.f - g);
    }
}

extern "C" void kernel_launch(void* const* d_in, const int* in_sizes, int n_in,
                              void* d_out, int out_size, void* d_ws, size_t ws_size,
                              hipStream_t stream) {
    const float* x       = (const float*)d_in[0];
    const float* maxgate = (const float*)d_in[1];
    const float* mb      = (const float*)d_in[2];
    const float* pconvs  = (const float*)d_in[3];
    const float* pbs     = (const float*)d_in[4];
    const float* pgates  = (const float*)d_in[5];
    const float* gbs     = (const float*)d_in[6];
    float* out           = (float*)d_out;

    const int blocks = 16 * 256 * NT;   // B * C * tiles-per-plane
    fused_densenet_kernel<<<blocks, TB, 0, stream>>>(
        x, maxgate, mb, pconvs, pbs, pgates, gbs, out);
}